// Round 21
// baseline (440.937 us; speedup 1.0000x reference)
//
#include <hip/hip_runtime.h>
#include <math.h>

#define HID 64
#define LR_ATT 0.2f
#define LR_ACT 0.01f
#define SCHUNK 1024   // elements per scan block

// ---------------- CSR build (once per call; graph shared by all 3 layers) ----------------

// Pass 1: per-dst count AND within-bucket rank in one atomic.
__global__ __launch_bounds__(256) void count_rank_kernel(
    const int* __restrict__ dst, int* __restrict__ counts,
    int* __restrict__ rank, int E)
{
    int i = blockIdx.x * blockDim.x + threadIdx.x;
    int stride = gridDim.x * blockDim.x;
    for (; i < E; i += stride)
        rank[i] = atomicAdd(&counts[dst[i]], 1);
}

// Hierarchical scan (n up to 256*SCHUNK): reduce -> top scan -> apply.
__global__ __launch_bounds__(256) void scan_reduce_kernel(
    const int* __restrict__ counts, int* __restrict__ part, int n)
{
    __shared__ int sdata[256];
    const int b = blockIdx.x, t = threadIdx.x;
    const int base = b * SCHUNK;
    int sum = 0;
    for (int i = base + t; i < n && i < base + SCHUNK; i += 256) sum += counts[i];
    sdata[t] = sum;
    __syncthreads();
    for (int off = 128; off; off >>= 1) {
        if (t < off) sdata[t] += sdata[t + off];
        __syncthreads();
    }
    if (t == 0) part[b] = sdata[0];
}

__global__ __launch_bounds__(256) void scan_top_kernel(
    int* __restrict__ part, int nPart, int* __restrict__ offsets, int n)
{
    __shared__ int sdata[256];
    const int t = threadIdx.x;
    int v = (t < nPart) ? part[t] : 0;
    sdata[t] = v;
    __syncthreads();
    for (int off = 1; off < 256; off <<= 1) {
        int u = (t >= off) ? sdata[t - off] : 0;
        __syncthreads();
        sdata[t] += u;
        __syncthreads();
    }
    if (t < nPart) part[t] = sdata[t] - v;     // exclusive block prefix
    if (t == 255) offsets[n] = sdata[255];     // total == E
}

__global__ __launch_bounds__(256) void scan_apply_kernel(
    const int* __restrict__ counts, const int* __restrict__ part,
    int* __restrict__ offsets, int n)
{
    __shared__ int sdata[256];
    const int b = blockIdx.x, t = threadIdx.x;
    const int i0 = b * SCHUNK + t * 4;
    int c[4];
    int s = 0;
    #pragma unroll
    for (int j = 0; j < 4; ++j) {
        int i = i0 + j;
        c[j] = (i < n) ? counts[i] : 0;
        s += c[j];
    }
    sdata[t] = s;
    __syncthreads();
    for (int off = 1; off < 256; off <<= 1) {
        int u = (t >= off) ? sdata[t - off] : 0;
        __syncthreads();
        sdata[t] += u;
        __syncthreads();
    }
    int run = part[b] + sdata[t] - s;          // exclusive base for this thread
    #pragma unroll
    for (int j = 0; j < 4; ++j) {
        int i = i0 + j;
        if (i < n) offsets[i] = run;
        run += c[j];
    }
}

// Pass 2: independent random writes (full MLP, no atomic dependency).
__global__ __launch_bounds__(256) void scatter_write_kernel(
    const int* __restrict__ src, const int* __restrict__ dst,
    const int* __restrict__ rank, const int* __restrict__ offsets,
    int* __restrict__ sorted_src, int E)
{
    int i = blockIdx.x * blockDim.x + threadIdx.x;
    int stride = gridDim.x * blockDim.x;
    for (; i < E; i += stride)
        sorted_src[offsets[dst[i]] + rank[i]] = src[i];
}

// ---------------- per-layer kernels ----------------

// h = hin @ W (K x 64). W TRANSPOSED in LDS: Wt[c][K+4] (pad -> stride 132
// == 4 mod 32, so per-lane ds_read_b128 windows tile all banks evenly).
// Per node: 32 b128 LDS reads (vs 128 b32) + wave-uniform float4 x loads.
// 4 independent accumulators break the fmac dependency chain.
template<int K>
__global__ __launch_bounds__(256) void gemm_att_ldsT_kernel(
    const float* __restrict__ hin, const float* __restrict__ W,
    const float* __restrict__ a_src, const float* __restrict__ a_dst,
    float* __restrict__ hout, float* __restrict__ al_s, float* __restrict__ al_d,
    int n_nodes)
{
    const int KP = K + 4;
    __shared__ float Wt[HID * (K + 4)];
    for (int i = threadIdx.x; i < K * HID; i += blockDim.x) {
        int k = i >> 6, c = i & 63;
        Wt[c * KP + k] = W[i];
    }
    __syncthreads();

    const int lane = threadIdx.x & 63;
    const int wib  = threadIdx.x >> 6;
    const int wpb  = blockDim.x >> 6;
    int wid = blockIdx.x * wpb + wib;
    int nw  = gridDim.x * wpb;

    const float as = a_src[lane];
    const float ad = a_dst[lane];
    const float* wrow = &Wt[lane * KP];

    for (int nn = wid; nn < n_nodes; nn += nw) {
        const float4* xr4 = (const float4*)(hin + (size_t)nn * K);
        float a0 = 0.f, a1 = 0.f, a2 = 0.f, a3 = 0.f;
        #pragma unroll
        for (int k4 = 0; k4 < K / 4; ++k4) {
            const float4 xv = xr4[k4];                    // wave-uniform
            const float4 wv = *(const float4*)&wrow[k4 * 4];
            a0 = fmaf(xv.x, wv.x, a0);
            a1 = fmaf(xv.y, wv.y, a1);
            a2 = fmaf(xv.z, wv.z, a2);
            a3 = fmaf(xv.w, wv.w, a3);
        }
        float acc = (a0 + a1) + (a2 + a3);

        hout[(size_t)nn * HID + lane] = acc;

        float ps = acc * as, pd = acc * ad;
        #pragma unroll
        for (int off = 32; off; off >>= 1) {
            ps += __shfl_xor(ps, off);
            pd += __shfl_xor(pd, off);
        }
        if (lane == 0) {
            al_s[nn] = ps;
            al_d[nn] = pd;
        }
    }
}

// K=64 register version: W column in 64 VGPRs, row broadcast via shfl.
__global__ __launch_bounds__(256) void gemm_att_reg64_kernel(
    const float* __restrict__ hin, const float* __restrict__ W,
    const float* __restrict__ a_src, const float* __restrict__ a_dst,
    float* __restrict__ hout, float* __restrict__ al_s, float* __restrict__ al_d,
    int n_nodes)
{
    const int lane = threadIdx.x & 63;
    const int wib  = threadIdx.x >> 6;
    const int wpb  = blockDim.x >> 6;
    int wid = blockIdx.x * wpb + wib;
    int nw  = gridDim.x * wpb;

    float wreg[64];
    #pragma unroll
    for (int k = 0; k < 64; ++k) wreg[k] = W[k * HID + lane];

    const float as = a_src[lane];
    const float ad = a_dst[lane];

    for (int nn = wid; nn < n_nodes; nn += nw) {
        float r = hin[(size_t)nn * 64 + lane];
        float acc = 0.f;
        #pragma unroll
        for (int k = 0; k < 64; ++k)
            acc = fmaf(__shfl(r, k), wreg[k], acc);

        hout[(size_t)nn * HID + lane] = acc;

        float ps = acc * as, pd = acc * ad;
        #pragma unroll
        for (int off = 32; off; off >>= 1) {
            ps += __shfl_xor(ps, off);
            pd += __shfl_xor(pd, off);
        }
        if (lane == 0) {
            al_s[nn] = ps;
            al_d[nn] = pd;
        }
    }
}

// One wave per dst node. Phase 1: lane ℓ preloads edge ℓ's src + logit
// (coalesced), wave-max, p = exp(e-m) per lane, denominator via ONE wave
// reduce -> softmax fully resolved before the gather loop. Phase 2: quarter-
// wave per edge; s,p broadcast by shfl (no memory deps), one float4 gather +
// 4 fma per quarter per iteration. Degree>64 handled by a rare tail loop.
template<bool FUSE_HEAD>
__global__ __launch_bounds__(256) void node_agg_kernel(
    const int* __restrict__ offsets, const int* __restrict__ sorted_src,
    const float* __restrict__ al_s, const float* __restrict__ al_d,
    const float* __restrict__ h, const float* __restrict__ b,
    float* __restrict__ hout,
    const float* __restrict__ Wout, const float* __restrict__ bout,
    float* __restrict__ out, int n_nodes)
{
    const int lane = threadIdx.x & 63;
    const int q    = lane >> 4;        // quarter: which edge of the 4
    const int ch   = (lane & 15) * 4;  // float4 channel quad
    const int wib  = threadIdx.x >> 6;
    const int wpb  = blockDim.x >> 6;
    int wid = blockIdx.x * wpb + wib;
    int nw  = gridDim.x * wpb;

    const float4 bc = *(const float4*)&b[ch];
    const float4 wc = FUSE_HEAD ? *(const float4*)&Wout[ch] : float4{0.f,0.f,0.f,0.f};

    for (int d = wid; d < n_nodes; d += nw) {
        const float ald = al_d[d];
        float e0 = al_s[d] + ald;           // self-loop logit
        e0 = (e0 > 0.f) ? e0 : LR_ATT * e0;

        const int k0  = offsets[d];
        const int k1  = offsets[d + 1];
        const int deg = k1 - k0;

        // ---- phase 1: preload + max + softmax weights + denominator ----
        int   sA = d;
        float eA = __int_as_float(0xff800000);  // -inf
        if (lane < deg) {
            sA = sorted_src[k0 + lane];
            float e = al_s[sA] + ald;
            eA = (e > 0.f) ? e : LR_ATT * e;
        }
        float lm = fmaxf(e0, eA);
        for (int k = k0 + 64 + lane; k < k1; k += 64) {  // rare: deg > 64
            int s = sorted_src[k];
            float e = al_s[s] + ald;
            e = (e > 0.f) ? e : LR_ATT * e;
            lm = fmaxf(lm, e);
        }
        #pragma unroll
        for (int off = 32; off; off >>= 1)
            lm = fmaxf(lm, __shfl_xor(lm, off));
        const float m = lm;

        const float ex0 = __expf(e0 - m);
        float pA = (lane < deg) ? __expf(eA - m) : 0.f;
        float ssum = pA;
        #pragma unroll
        for (int off = 32; off; off >>= 1) ssum += __shfl_xor(ssum, off);
        float sum = ssum + ex0;                 // wave-uniform denominator

        // ---- phase 2: gather-accumulate, 4 edges / iteration ----
        const float4 hd = *(const float4*)&h[(size_t)d * HID + ch];
        float exq = (q == 0) ? ex0 : 0.f;       // self-loop in quarter 0
        float4 acc;
        acc.x = exq * hd.x; acc.y = exq * hd.y;
        acc.z = exq * hd.z; acc.w = exq * hd.w;

        const int mainN = min(deg, 64);
        for (int k = 0; k < mainN; k += 4) {
            int   s = __shfl(sA, k + q);        // broadcast, no memory dep
            float p = __shfl(pA, k + q);        // 0 beyond deg
            const float4 hv = *(const float4*)&h[(size_t)s * HID + ch];
            acc.x = fmaf(p, hv.x, acc.x);
            acc.y = fmaf(p, hv.y, acc.y);
            acc.z = fmaf(p, hv.z, acc.z);
            acc.w = fmaf(p, hv.w, acc.w);
        }

        // rare tail: deg > 64
        float sumX = 0.f;
        for (int k = k0 + 64; k < k1; k += 4) {
            int kk = k + q;
            bool valid = (kk < k1);
            int s = valid ? sorted_src[kk] : d;
            float e = al_s[s] + ald;
            e = (e > 0.f) ? e : LR_ATT * e;
            float ex = valid ? __expf(e - m) : 0.f;
            const float4 hv = *(const float4*)&h[(size_t)s * HID + ch];
            acc.x = fmaf(ex, hv.x, acc.x);
            acc.y = fmaf(ex, hv.y, acc.y);
            acc.z = fmaf(ex, hv.z, acc.z);
            acc.w = fmaf(ex, hv.w, acc.w);
            sumX += ex;
        }

        // ---- combine the four quarters ----
        #pragma unroll
        for (int off = 16; off <= 32; off <<= 1) {
            acc.x += __shfl_xor(acc.x, off);
            acc.y += __shfl_xor(acc.y, off);
            acc.z += __shfl_xor(acc.z, off);
            acc.w += __shfl_xor(acc.w, off);
            sumX  += __shfl_xor(sumX, off);
        }
        sum += sumX;

        float inv = 1.f / sum;
        float4 v;
        v.x = fmaf(acc.x, inv, bc.x); v.y = fmaf(acc.y, inv, bc.y);
        v.z = fmaf(acc.z, inv, bc.z); v.w = fmaf(acc.w, inv, bc.w);
        v.x = (v.x > 0.f) ? v.x : LR_ACT * v.x;
        v.y = (v.y > 0.f) ? v.y : LR_ACT * v.y;
        v.z = (v.z > 0.f) ? v.z : LR_ACT * v.z;
        v.w = (v.w > 0.f) ? v.w : LR_ACT * v.w;

        if (!FUSE_HEAD) {
            if (lane < 16) *(float4*)&hout[(size_t)d * HID + ch] = v;
        } else {
            float t = v.x * wc.x + v.y * wc.y + v.z * wc.z + v.w * wc.w;
            #pragma unroll
            for (int off = 8; off; off >>= 1) t += __shfl_xor(t, off);
            if (lane == 0) out[d] = t + bout[0];
        }
    }
}

extern "C" void kernel_launch(void* const* d_in, const int* in_sizes, int n_in,
                              void* d_out, int out_size, void* d_ws, size_t ws_size,
                              hipStream_t stream)
{
    const float* x      = (const float*)d_in[0];
    const int*   ei     = (const int*)  d_in[1];
    const float* W1     = (const float*)d_in[2];
    const float* a_src1 = (const float*)d_in[3];
    const float* a_dst1 = (const float*)d_in[4];
    const float* b1     = (const float*)d_in[5];
    const float* W2     = (const float*)d_in[6];
    const float* a_src2 = (const float*)d_in[7];
    const float* a_dst2 = (const float*)d_in[8];
    const float* b2     = (const float*)d_in[9];
    const float* W3     = (const float*)d_in[10];
    const float* a_src3 = (const float*)d_in[11];
    const float* a_dst3 = (const float*)d_in[12];
    const float* b3     = (const float*)d_in[13];
    const float* W_out  = (const float*)d_in[14];
    const float* b_out  = (const float*)d_in[15];
    float* out = (float*)d_out;

    const int n = out_size;           // 50000 nodes
    const int E = in_sizes[1] / 2;    // 1.6M edges

    const int* src = ei;
    const int* dst = ei + E;

    // workspace layout
    float* ws   = (float*)d_ws;
    float* hA   = ws;                        // n*64
    float* hB   = hA + (size_t)n * HID;      // n*64
    float* al_s = hB + (size_t)n * HID;      // n
    float* al_d = al_s + n;                  // n
    int* counts     = (int*)(al_d + n);      // n
    int* offsets    = counts + n;            // n+1
    int* part       = offsets + (n + 1);     // 256
    int* rank       = part + 256;            // E
    int* sorted_src = rank + E;              // E

    dim3 blk(256);
    const int gemm_grid = 1024;
    const int edge_grid = 4096;
    const int node_grid = (n + 3) / 4;             // 4 waves/block, 1 wave/node
    const int nPart     = (n + SCHUNK - 1) / SCHUNK;  // 49 scan blocks

    // ---- CSR build (graph is layer-invariant) ----
    (void)hipMemsetAsync(counts, 0, (size_t)n * sizeof(int), stream);
    count_rank_kernel<<<edge_grid, blk, 0, stream>>>(dst, counts, rank, E);
    scan_reduce_kernel<<<nPart, blk, 0, stream>>>(counts, part, n);
    scan_top_kernel<<<1, blk, 0, stream>>>(part, nPart, offsets, n);
    scan_apply_kernel<<<nPart, blk, 0, stream>>>(counts, part, offsets, n);
    scatter_write_kernel<<<edge_grid, blk, 0, stream>>>(src, dst, rank, offsets,
        sorted_src, E);

    // ---- layer 1 (K = 128) ----
    gemm_att_ldsT_kernel<128><<<gemm_grid, blk, 0, stream>>>(x, W1, a_src1, a_dst1,
        hA, al_s, al_d, n);
    node_agg_kernel<false><<<node_grid, blk, 0, stream>>>(offsets, sorted_src,
        al_s, al_d, hA, b1, hB, nullptr, nullptr, nullptr, n);

    // ---- layer 2 (K = 64) ----
    gemm_att_reg64_kernel<<<gemm_grid, blk, 0, stream>>>(hB, W2, a_src2, a_dst2,
        hA, al_s, al_d, n);
    node_agg_kernel<false><<<node_grid, blk, 0, stream>>>(offsets, sorted_src,
        al_s, al_d, hA, b2, hB, nullptr, nullptr, nullptr, n);

    // ---- layer 3 (K = 64) + fused output head ----
    gemm_att_reg64_kernel<<<gemm_grid, blk, 0, stream>>>(hB, W3, a_src3, a_dst3,
        hA, al_s, al_d, n);
    node_agg_kernel<true><<<node_grid, blk, 0, stream>>>(offsets, sorted_src,
        al_s, al_d, hA, b3, nullptr, W_out, b_out, out, n);
}

// Round 22
// 426.537 us; speedup vs baseline: 1.0338x; 1.0338x over previous
//
#include <hip/hip_runtime.h>
#include <math.h>

#define HID 64
#define LR_ATT 0.2f
#define LR_ACT 0.01f
#define SCHUNK 1024   // elements per scan block

// ---------------- CSR build (once per call; graph shared by all 3 layers) ----------------

// Pass 1: per-dst count AND within-bucket rank in one atomic.
__global__ __launch_bounds__(256) void count_rank_kernel(
    const int* __restrict__ dst, int* __restrict__ counts,
    int* __restrict__ rank, int E)
{
    int i = blockIdx.x * blockDim.x + threadIdx.x;
    int stride = gridDim.x * blockDim.x;
    for (; i < E; i += stride)
        rank[i] = atomicAdd(&counts[dst[i]], 1);
}

// Hierarchical scan (n up to 256*SCHUNK): reduce -> top scan -> apply.
__global__ __launch_bounds__(256) void scan_reduce_kernel(
    const int* __restrict__ counts, int* __restrict__ part, int n)
{
    __shared__ int sdata[256];
    const int b = blockIdx.x, t = threadIdx.x;
    const int base = b * SCHUNK;
    int sum = 0;
    for (int i = base + t; i < n && i < base + SCHUNK; i += 256) sum += counts[i];
    sdata[t] = sum;
    __syncthreads();
    for (int off = 128; off; off >>= 1) {
        if (t < off) sdata[t] += sdata[t + off];
        __syncthreads();
    }
    if (t == 0) part[b] = sdata[0];
}

__global__ __launch_bounds__(256) void scan_top_kernel(
    int* __restrict__ part, int nPart, int* __restrict__ offsets, int n)
{
    __shared__ int sdata[256];
    const int t = threadIdx.x;
    int v = (t < nPart) ? part[t] : 0;
    sdata[t] = v;
    __syncthreads();
    for (int off = 1; off < 256; off <<= 1) {
        int u = (t >= off) ? sdata[t - off] : 0;
        __syncthreads();
        sdata[t] += u;
        __syncthreads();
    }
    if (t < nPart) part[t] = sdata[t] - v;     // exclusive block prefix
    if (t == 255) offsets[n] = sdata[255];     // total == E
}

__global__ __launch_bounds__(256) void scan_apply_kernel(
    const int* __restrict__ counts, const int* __restrict__ part,
    int* __restrict__ offsets, int n)
{
    __shared__ int sdata[256];
    const int b = blockIdx.x, t = threadIdx.x;
    const int i0 = b * SCHUNK + t * 4;
    int c[4];
    int s = 0;
    #pragma unroll
    for (int j = 0; j < 4; ++j) {
        int i = i0 + j;
        c[j] = (i < n) ? counts[i] : 0;
        s += c[j];
    }
    sdata[t] = s;
    __syncthreads();
    for (int off = 1; off < 256; off <<= 1) {
        int u = (t >= off) ? sdata[t - off] : 0;
        __syncthreads();
        sdata[t] += u;
        __syncthreads();
    }
    int run = part[b] + sdata[t] - s;          // exclusive base for this thread
    #pragma unroll
    for (int j = 0; j < 4; ++j) {
        int i = i0 + j;
        if (i < n) offsets[i] = run;
        run += c[j];
    }
}

// Pass 2: independent random writes (full MLP, no atomic dependency).
__global__ __launch_bounds__(256) void scatter_write_kernel(
    const int* __restrict__ src, const int* __restrict__ dst,
    const int* __restrict__ rank, const int* __restrict__ offsets,
    int* __restrict__ sorted_src, int E)
{
    int i = blockIdx.x * blockDim.x + threadIdx.x;
    int stride = gridDim.x * blockDim.x;
    for (; i < E; i += stride)
        sorted_src[offsets[dst[i]] + rank[i]] = src[i];
}

// ---------------- per-layer kernels ----------------

// h = hin @ W (K x 64). W in LDS, layout Wl[k*64+lane]: bank = lane mod 32
// -> 2 lanes/bank (free). FOUR nodes per wave: one Wl read feeds 4 fmas
// (LDS reads/node /4), x rows as wave-uniform float4, 4 independent
// accumulators give 4-way ILP over the fma latency.
template<int K>
__global__ __launch_bounds__(256) void gemm_att_lds4_kernel(
    const float* __restrict__ hin, const float* __restrict__ W,
    const float* __restrict__ a_src, const float* __restrict__ a_dst,
    float* __restrict__ hout, float* __restrict__ al_s, float* __restrict__ al_d,
    int n_nodes)
{
    __shared__ float Wl[K * HID];
    for (int i = threadIdx.x; i < K * HID; i += blockDim.x) Wl[i] = W[i];
    __syncthreads();

    const int lane = threadIdx.x & 63;
    const int wib  = threadIdx.x >> 6;
    const int wpb  = blockDim.x >> 6;
    int wid = blockIdx.x * wpb + wib;
    int nw  = gridDim.x * wpb;

    const float as = a_src[lane];
    const float ad = a_dst[lane];

    for (int base = wid * 4; base < n_nodes; base += nw * 4) {
        const int nv = min(4, n_nodes - base);
        const float4* xr0 = (const float4*)(hin + (size_t)base * K);
        const float4* xr1 = (const float4*)(hin + (size_t)(base + (nv > 1 ? 1 : 0)) * K);
        const float4* xr2 = (const float4*)(hin + (size_t)(base + (nv > 2 ? 2 : 0)) * K);
        const float4* xr3 = (const float4*)(hin + (size_t)(base + (nv > 3 ? 3 : 0)) * K);

        float a0 = 0.f, a1 = 0.f, a2 = 0.f, a3 = 0.f;
        #pragma unroll 8
        for (int k4 = 0; k4 < K / 4; ++k4) {
            const float4 x0 = xr0[k4];
            const float4 x1 = xr1[k4];
            const float4 x2 = xr2[k4];
            const float4 x3 = xr3[k4];
            const float w0 = Wl[(k4 * 4 + 0) * HID + lane];
            const float w1 = Wl[(k4 * 4 + 1) * HID + lane];
            const float w2 = Wl[(k4 * 4 + 2) * HID + lane];
            const float w3 = Wl[(k4 * 4 + 3) * HID + lane];
            a0 = fmaf(x0.x, w0, a0); a0 = fmaf(x0.y, w1, a0);
            a0 = fmaf(x0.z, w2, a0); a0 = fmaf(x0.w, w3, a0);
            a1 = fmaf(x1.x, w0, a1); a1 = fmaf(x1.y, w1, a1);
            a1 = fmaf(x1.z, w2, a1); a1 = fmaf(x1.w, w3, a1);
            a2 = fmaf(x2.x, w0, a2); a2 = fmaf(x2.y, w1, a2);
            a2 = fmaf(x2.z, w2, a2); a2 = fmaf(x2.w, w3, a2);
            a3 = fmaf(x3.x, w0, a3); a3 = fmaf(x3.y, w1, a3);
            a3 = fmaf(x3.z, w2, a3); a3 = fmaf(x3.w, w3, a3);
        }

        const float accs[4] = {a0, a1, a2, a3};
        #pragma unroll
        for (int j = 0; j < 4; ++j) {
            if (j < nv) {
                const float acc = accs[j];
                hout[(size_t)(base + j) * HID + lane] = acc;
                float ps = acc * as, pd = acc * ad;
                #pragma unroll
                for (int off = 32; off; off >>= 1) {
                    ps += __shfl_xor(ps, off);
                    pd += __shfl_xor(pd, off);
                }
                if (lane == 0) {
                    al_s[base + j] = ps;
                    al_d[base + j] = pd;
                }
            }
        }
    }
}

// K=64 register version: W column in 64 VGPRs, row broadcast via shfl.
__global__ __launch_bounds__(256) void gemm_att_reg64_kernel(
    const float* __restrict__ hin, const float* __restrict__ W,
    const float* __restrict__ a_src, const float* __restrict__ a_dst,
    float* __restrict__ hout, float* __restrict__ al_s, float* __restrict__ al_d,
    int n_nodes)
{
    const int lane = threadIdx.x & 63;
    const int wib  = threadIdx.x >> 6;
    const int wpb  = blockDim.x >> 6;
    int wid = blockIdx.x * wpb + wib;
    int nw  = gridDim.x * wpb;

    float wreg[64];
    #pragma unroll
    for (int k = 0; k < 64; ++k) wreg[k] = W[k * HID + lane];

    const float as = a_src[lane];
    const float ad = a_dst[lane];

    for (int nn = wid; nn < n_nodes; nn += nw) {
        float r = hin[(size_t)nn * 64 + lane];
        float acc = 0.f;
        #pragma unroll
        for (int k = 0; k < 64; ++k)
            acc = fmaf(__shfl(r, k), wreg[k], acc);

        hout[(size_t)nn * HID + lane] = acc;

        float ps = acc * as, pd = acc * ad;
        #pragma unroll
        for (int off = 32; off; off >>= 1) {
            ps += __shfl_xor(ps, off);
            pd += __shfl_xor(pd, off);
        }
        if (lane == 0) {
            al_s[nn] = ps;
            al_d[nn] = pd;
        }
    }
}

// One wave per dst node. Phase 1: lane ℓ preloads edge ℓ's src + logit
// (coalesced), wave-max, p = exp(e-m) per lane, denominator via ONE wave
// reduce -> softmax fully resolved before the gather loop. Phase 2: quarter-
// wave per edge; s,p broadcast by shfl (no memory deps), one float4 gather +
// 4 fma per quarter per iteration. Degree>64 handled by a rare tail loop.
template<bool FUSE_HEAD>
__global__ __launch_bounds__(256) void node_agg_kernel(
    const int* __restrict__ offsets, const int* __restrict__ sorted_src,
    const float* __restrict__ al_s, const float* __restrict__ al_d,
    const float* __restrict__ h, const float* __restrict__ b,
    float* __restrict__ hout,
    const float* __restrict__ Wout, const float* __restrict__ bout,
    float* __restrict__ out, int n_nodes)
{
    const int lane = threadIdx.x & 63;
    const int q    = lane >> 4;        // quarter: which edge of the 4
    const int ch   = (lane & 15) * 4;  // float4 channel quad
    const int wib  = threadIdx.x >> 6;
    const int wpb  = blockDim.x >> 6;
    int wid = blockIdx.x * wpb + wib;
    int nw  = gridDim.x * wpb;

    const float4 bc = *(const float4*)&b[ch];
    const float4 wc = FUSE_HEAD ? *(const float4*)&Wout[ch] : float4{0.f,0.f,0.f,0.f};

    for (int d = wid; d < n_nodes; d += nw) {
        const float ald = al_d[d];
        float e0 = al_s[d] + ald;           // self-loop logit
        e0 = (e0 > 0.f) ? e0 : LR_ATT * e0;

        const int k0  = offsets[d];
        const int k1  = offsets[d + 1];
        const int deg = k1 - k0;

        // ---- phase 1: preload + max + softmax weights + denominator ----
        int   sA = d;
        float eA = __int_as_float(0xff800000);  // -inf
        if (lane < deg) {
            sA = sorted_src[k0 + lane];
            float e = al_s[sA] + ald;
            eA = (e > 0.f) ? e : LR_ATT * e;
        }
        float lm = fmaxf(e0, eA);
        for (int k = k0 + 64 + lane; k < k1; k += 64) {  // rare: deg > 64
            int s = sorted_src[k];
            float e = al_s[s] + ald;
            e = (e > 0.f) ? e : LR_ATT * e;
            lm = fmaxf(lm, e);
        }
        #pragma unroll
        for (int off = 32; off; off >>= 1)
            lm = fmaxf(lm, __shfl_xor(lm, off));
        const float m = lm;

        const float ex0 = __expf(e0 - m);
        float pA = (lane < deg) ? __expf(eA - m) : 0.f;
        float ssum = pA;
        #pragma unroll
        for (int off = 32; off; off >>= 1) ssum += __shfl_xor(ssum, off);
        float sum = ssum + ex0;                 // wave-uniform denominator

        // ---- phase 2: gather-accumulate, 4 edges / iteration ----
        const float4 hd = *(const float4*)&h[(size_t)d * HID + ch];
        float exq = (q == 0) ? ex0 : 0.f;       // self-loop in quarter 0
        float4 acc;
        acc.x = exq * hd.x; acc.y = exq * hd.y;
        acc.z = exq * hd.z; acc.w = exq * hd.w;

        const int mainN = min(deg, 64);
        for (int k = 0; k < mainN; k += 4) {
            int   s = __shfl(sA, k + q);        // broadcast, no memory dep
            float p = __shfl(pA, k + q);        // 0 beyond deg
            const float4 hv = *(const float4*)&h[(size_t)s * HID + ch];
            acc.x = fmaf(p, hv.x, acc.x);
            acc.y = fmaf(p, hv.y, acc.y);
            acc.z = fmaf(p, hv.z, acc.z);
            acc.w = fmaf(p, hv.w, acc.w);
        }

        // rare tail: deg > 64
        float sumX = 0.f;
        for (int k = k0 + 64; k < k1; k += 4) {
            int kk = k + q;
            bool valid = (kk < k1);
            int s = valid ? sorted_src[kk] : d;
            float e = al_s[s] + ald;
            e = (e > 0.f) ? e : LR_ATT * e;
            float ex = valid ? __expf(e - m) : 0.f;
            const float4 hv = *(const float4*)&h[(size_t)s * HID + ch];
            acc.x = fmaf(ex, hv.x, acc.x);
            acc.y = fmaf(ex, hv.y, acc.y);
            acc.z = fmaf(ex, hv.z, acc.z);
            acc.w = fmaf(ex, hv.w, acc.w);
            sumX += ex;
        }

        // ---- combine the four quarters ----
        #pragma unroll
        for (int off = 16; off <= 32; off <<= 1) {
            acc.x += __shfl_xor(acc.x, off);
            acc.y += __shfl_xor(acc.y, off);
            acc.z += __shfl_xor(acc.z, off);
            acc.w += __shfl_xor(acc.w, off);
            sumX  += __shfl_xor(sumX, off);
        }
        sum += sumX;

        float inv = 1.f / sum;
        float4 v;
        v.x = fmaf(acc.x, inv, bc.x); v.y = fmaf(acc.y, inv, bc.y);
        v.z = fmaf(acc.z, inv, bc.z); v.w = fmaf(acc.w, inv, bc.w);
        v.x = (v.x > 0.f) ? v.x : LR_ACT * v.x;
        v.y = (v.y > 0.f) ? v.y : LR_ACT * v.y;
        v.z = (v.z > 0.f) ? v.z : LR_ACT * v.z;
        v.w = (v.w > 0.f) ? v.w : LR_ACT * v.w;

        if (!FUSE_HEAD) {
            if (lane < 16) *(float4*)&hout[(size_t)d * HID + ch] = v;
        } else {
            float t = v.x * wc.x + v.y * wc.y + v.z * wc.z + v.w * wc.w;
            #pragma unroll
            for (int off = 8; off; off >>= 1) t += __shfl_xor(t, off);
            if (lane == 0) out[d] = t + bout[0];
        }
    }
}

extern "C" void kernel_launch(void* const* d_in, const int* in_sizes, int n_in,
                              void* d_out, int out_size, void* d_ws, size_t ws_size,
                              hipStream_t stream)
{
    const float* x      = (const float*)d_in[0];
    const int*   ei     = (const int*)  d_in[1];
    const float* W1     = (const float*)d_in[2];
    const float* a_src1 = (const float*)d_in[3];
    const float* a_dst1 = (const float*)d_in[4];
    const float* b1     = (const float*)d_in[5];
    const float* W2     = (const float*)d_in[6];
    const float* a_src2 = (const float*)d_in[7];
    const float* a_dst2 = (const float*)d_in[8];
    const float* b2     = (const float*)d_in[9];
    const float* W3     = (const float*)d_in[10];
    const float* a_src3 = (const float*)d_in[11];
    const float* a_dst3 = (const float*)d_in[12];
    const float* b3     = (const float*)d_in[13];
    const float* W_out  = (const float*)d_in[14];
    const float* b_out  = (const float*)d_in[15];
    float* out = (float*)d_out;

    const int n = out_size;           // 50000 nodes
    const int E = in_sizes[1] / 2;    // 1.6M edges

    const int* src = ei;
    const int* dst = ei + E;

    // workspace layout
    float* ws   = (float*)d_ws;
    float* hA   = ws;                        // n*64
    float* hB   = hA + (size_t)n * HID;      // n*64
    float* al_s = hB + (size_t)n * HID;      // n
    float* al_d = al_s + n;                  // n
    int* counts     = (int*)(al_d + n);      // n
    int* offsets    = counts + n;            // n+1
    int* part       = offsets + (n + 1);     // 256
    int* rank       = part + 256;            // E
    int* sorted_src = rank + E;              // E

    dim3 blk(256);
    const int gemm_grid = 1024;
    const int edge_grid = 4096;
    const int node_grid = (n + 3) / 4;             // 4 waves/block, 1 wave/node
    const int nPart     = (n + SCHUNK - 1) / SCHUNK;  // 49 scan blocks

    // ---- CSR build (graph is layer-invariant) ----
    (void)hipMemsetAsync(counts, 0, (size_t)n * sizeof(int), stream);
    count_rank_kernel<<<edge_grid, blk, 0, stream>>>(dst, counts, rank, E);
    scan_reduce_kernel<<<nPart, blk, 0, stream>>>(counts, part, n);
    scan_top_kernel<<<1, blk, 0, stream>>>(part, nPart, offsets, n);
    scan_apply_kernel<<<nPart, blk, 0, stream>>>(counts, part, offsets, n);
    scatter_write_kernel<<<edge_grid, blk, 0, stream>>>(src, dst, rank, offsets,
        sorted_src, E);

    // ---- layer 1 (K = 128) ----
    gemm_att_lds4_kernel<128><<<gemm_grid, blk, 0, stream>>>(x, W1, a_src1, a_dst1,
        hA, al_s, al_d, n);
    node_agg_kernel<false><<<node_grid, blk, 0, stream>>>(offsets, sorted_src,
        al_s, al_d, hA, b1, hB, nullptr, nullptr, nullptr, n);

    // ---- layer 2 (K = 64) ----
    gemm_att_reg64_kernel<<<gemm_grid, blk, 0, stream>>>(hB, W2, a_src2, a_dst2,
        hA, al_s, al_d, n);
    node_agg_kernel<false><<<node_grid, blk, 0, stream>>>(offsets, sorted_src,
        al_s, al_d, hA, b2, hB, nullptr, nullptr, nullptr, n);

    // ---- layer 3 (K = 64) + fused output head ----
    gemm_att_reg64_kernel<<<gemm_grid, blk, 0, stream>>>(hB, W3, a_src3, a_dst3,
        hA, al_s, al_d, n);
    node_agg_kernel<true><<<node_grid, blk, 0, stream>>>(offsets, sorted_src,
        al_s, al_d, hA, b3, nullptr, W_out, b_out, out, n);
}

// Round 23
// 410.372 us; speedup vs baseline: 1.0745x; 1.0394x over previous
//
#include <hip/hip_runtime.h>
#include <math.h>

#define HID 64
#define LR_ATT 0.2f
#define LR_ACT 0.01f
#define SCHUNK 1024   // elements per scan block

// ---------------- CSR build (once per call; graph shared by all 3 layers) ----------------

// Pass 1: per-dst count AND within-bucket rank in one atomic.
__global__ __launch_bounds__(256) void count_rank_kernel(
    const int* __restrict__ dst, int* __restrict__ counts,
    int* __restrict__ rank, int E)
{
    int i = blockIdx.x * blockDim.x + threadIdx.x;
    int stride = gridDim.x * blockDim.x;
    for (; i < E; i += stride)
        rank[i] = atomicAdd(&counts[dst[i]], 1);
}

// Hierarchical scan (n up to 256*SCHUNK): reduce -> top scan -> apply.
__global__ __launch_bounds__(256) void scan_reduce_kernel(
    const int* __restrict__ counts, int* __restrict__ part, int n)
{
    __shared__ int sdata[256];
    const int b = blockIdx.x, t = threadIdx.x;
    const int base = b * SCHUNK;
    int sum = 0;
    for (int i = base + t; i < n && i < base + SCHUNK; i += 256) sum += counts[i];
    sdata[t] = sum;
    __syncthreads();
    for (int off = 128; off; off >>= 1) {
        if (t < off) sdata[t] += sdata[t + off];
        __syncthreads();
    }
    if (t == 0) part[b] = sdata[0];
}

__global__ __launch_bounds__(256) void scan_top_kernel(
    int* __restrict__ part, int nPart, int* __restrict__ offsets, int n)
{
    __shared__ int sdata[256];
    const int t = threadIdx.x;
    int v = (t < nPart) ? part[t] : 0;
    sdata[t] = v;
    __syncthreads();
    for (int off = 1; off < 256; off <<= 1) {
        int u = (t >= off) ? sdata[t - off] : 0;
        __syncthreads();
        sdata[t] += u;
        __syncthreads();
    }
    if (t < nPart) part[t] = sdata[t] - v;     // exclusive block prefix
    if (t == 255) offsets[n] = sdata[255];     // total == E
}

__global__ __launch_bounds__(256) void scan_apply_kernel(
    const int* __restrict__ counts, const int* __restrict__ part,
    int* __restrict__ offsets, int n)
{
    __shared__ int sdata[256];
    const int b = blockIdx.x, t = threadIdx.x;
    const int i0 = b * SCHUNK + t * 4;
    int c[4];
    int s = 0;
    #pragma unroll
    for (int j = 0; j < 4; ++j) {
        int i = i0 + j;
        c[j] = (i < n) ? counts[i] : 0;
        s += c[j];
    }
    sdata[t] = s;
    __syncthreads();
    for (int off = 1; off < 256; off <<= 1) {
        int u = (t >= off) ? sdata[t - off] : 0;
        __syncthreads();
        sdata[t] += u;
        __syncthreads();
    }
    int run = part[b] + sdata[t] - s;          // exclusive base for this thread
    #pragma unroll
    for (int j = 0; j < 4; ++j) {
        int i = i0 + j;
        if (i < n) offsets[i] = run;
        run += c[j];
    }
}

// Pass 2: independent random writes (full MLP, no atomic dependency).
__global__ __launch_bounds__(256) void scatter_write_kernel(
    const int* __restrict__ src, const int* __restrict__ dst,
    const int* __restrict__ rank, const int* __restrict__ offsets,
    int* __restrict__ sorted_src, int E)
{
    int i = blockIdx.x * blockDim.x + threadIdx.x;
    int stride = gridDim.x * blockDim.x;
    for (; i < E; i += stride)
        sorted_src[offsets[dst[i]] + rank[i]] = src[i];
}

// ---------------- per-layer kernels ----------------

// h = hin @ W (K x 64). W in LDS, layout Wl[k*64+lane]: bank = lane mod 32
// -> 2 lanes/bank (free). FOUR nodes per wave: one Wl read feeds 4 fmas,
// x rows as wave-uniform float4, 4 independent accumulators for ILP.
template<int K>
__global__ __launch_bounds__(256) void gemm_att_lds4_kernel(
    const float* __restrict__ hin, const float* __restrict__ W,
    const float* __restrict__ a_src, const float* __restrict__ a_dst,
    float* __restrict__ hout, float* __restrict__ al_s, float* __restrict__ al_d,
    int n_nodes)
{
    __shared__ float Wl[K * HID];
    for (int i = threadIdx.x; i < K * HID; i += blockDim.x) Wl[i] = W[i];
    __syncthreads();

    const int lane = threadIdx.x & 63;
    const int wib  = threadIdx.x >> 6;
    const int wpb  = blockDim.x >> 6;
    int wid = blockIdx.x * wpb + wib;
    int nw  = gridDim.x * wpb;

    const float as = a_src[lane];
    const float ad = a_dst[lane];

    for (int base = wid * 4; base < n_nodes; base += nw * 4) {
        const int nv = min(4, n_nodes - base);
        const float4* xr0 = (const float4*)(hin + (size_t)base * K);
        const float4* xr1 = (const float4*)(hin + (size_t)(base + (nv > 1 ? 1 : 0)) * K);
        const float4* xr2 = (const float4*)(hin + (size_t)(base + (nv > 2 ? 2 : 0)) * K);
        const float4* xr3 = (const float4*)(hin + (size_t)(base + (nv > 3 ? 3 : 0)) * K);

        float a0 = 0.f, a1 = 0.f, a2 = 0.f, a3 = 0.f;
        #pragma unroll 8
        for (int k4 = 0; k4 < K / 4; ++k4) {
            const float4 x0 = xr0[k4];
            const float4 x1 = xr1[k4];
            const float4 x2 = xr2[k4];
            const float4 x3 = xr3[k4];
            const float w0 = Wl[(k4 * 4 + 0) * HID + lane];
            const float w1 = Wl[(k4 * 4 + 1) * HID + lane];
            const float w2 = Wl[(k4 * 4 + 2) * HID + lane];
            const float w3 = Wl[(k4 * 4 + 3) * HID + lane];
            a0 = fmaf(x0.x, w0, a0); a0 = fmaf(x0.y, w1, a0);
            a0 = fmaf(x0.z, w2, a0); a0 = fmaf(x0.w, w3, a0);
            a1 = fmaf(x1.x, w0, a1); a1 = fmaf(x1.y, w1, a1);
            a1 = fmaf(x1.z, w2, a1); a1 = fmaf(x1.w, w3, a1);
            a2 = fmaf(x2.x, w0, a2); a2 = fmaf(x2.y, w1, a2);
            a2 = fmaf(x2.z, w2, a2); a2 = fmaf(x2.w, w3, a2);
            a3 = fmaf(x3.x, w0, a3); a3 = fmaf(x3.y, w1, a3);
            a3 = fmaf(x3.z, w2, a3); a3 = fmaf(x3.w, w3, a3);
        }

        const float accs[4] = {a0, a1, a2, a3};
        #pragma unroll
        for (int j = 0; j < 4; ++j) {
            if (j < nv) {
                const float acc = accs[j];
                hout[(size_t)(base + j) * HID + lane] = acc;
                float ps = acc * as, pd = acc * ad;
                #pragma unroll
                for (int off = 32; off; off >>= 1) {
                    ps += __shfl_xor(ps, off);
                    pd += __shfl_xor(pd, off);
                }
                if (lane == 0) {
                    al_s[base + j] = ps;
                    al_d[base + j] = pd;
                }
            }
        }
    }
}

// One wave per dst node. Phase 1: lane ℓ preloads edge ℓ's src + logit
// (coalesced), wave-max, p = exp(e-m) per lane, denominator via ONE wave
// reduce. Phase 2: quarter-wave per edge, TWO independent gather+fma
// streams (8 edges/iteration) to double memory-level parallelism.
template<bool FUSE_HEAD>
__global__ __launch_bounds__(256) void node_agg_kernel(
    const int* __restrict__ offsets, const int* __restrict__ sorted_src,
    const float* __restrict__ al_s, const float* __restrict__ al_d,
    const float* __restrict__ h, const float* __restrict__ b,
    float* __restrict__ hout,
    const float* __restrict__ Wout, const float* __restrict__ bout,
    float* __restrict__ out, int n_nodes)
{
    const int lane = threadIdx.x & 63;
    const int q    = lane >> 4;        // quarter: which edge of the 4
    const int ch   = (lane & 15) * 4;  // float4 channel quad
    const int wib  = threadIdx.x >> 6;
    const int wpb  = blockDim.x >> 6;
    int wid = blockIdx.x * wpb + wib;
    int nw  = gridDim.x * wpb;

    const float4 bc = *(const float4*)&b[ch];
    const float4 wc = FUSE_HEAD ? *(const float4*)&Wout[ch] : float4{0.f,0.f,0.f,0.f};

    for (int d = wid; d < n_nodes; d += nw) {
        const float ald = al_d[d];
        float e0 = al_s[d] + ald;           // self-loop logit
        e0 = (e0 > 0.f) ? e0 : LR_ATT * e0;

        const int k0  = offsets[d];
        const int k1  = offsets[d + 1];
        const int deg = k1 - k0;

        // ---- phase 1: preload + max + softmax weights + denominator ----
        int   sA = d;
        float eA = __int_as_float(0xff800000);  // -inf
        if (lane < deg) {
            sA = sorted_src[k0 + lane];
            float e = al_s[sA] + ald;
            eA = (e > 0.f) ? e : LR_ATT * e;
        }
        float lm = fmaxf(e0, eA);
        for (int k = k0 + 64 + lane; k < k1; k += 64) {  // rare: deg > 64
            int s = sorted_src[k];
            float e = al_s[s] + ald;
            e = (e > 0.f) ? e : LR_ATT * e;
            lm = fmaxf(lm, e);
        }
        #pragma unroll
        for (int off = 32; off; off >>= 1)
            lm = fmaxf(lm, __shfl_xor(lm, off));
        const float m = lm;

        const float ex0 = __expf(e0 - m);
        float pA = (lane < deg) ? __expf(eA - m) : 0.f;
        float ssum = pA;
        #pragma unroll
        for (int off = 32; off; off >>= 1) ssum += __shfl_xor(ssum, off);
        float sum = ssum + ex0;                 // wave-uniform denominator

        // ---- phase 2: gather-accumulate, 2 streams x 4 edges ----
        const float4 hd = *(const float4*)&h[(size_t)d * HID + ch];
        float exq = (q == 0) ? ex0 : 0.f;       // self-loop in quarter 0
        float4 acc, acc2;
        acc.x  = exq * hd.x; acc.y  = exq * hd.y;
        acc.z  = exq * hd.z; acc.w  = exq * hd.w;
        acc2.x = 0.f; acc2.y = 0.f; acc2.z = 0.f; acc2.w = 0.f;

        const int mainN = min(deg, 64);
        int k = 0;
        for (; k + 8 <= mainN; k += 8) {
            int   s0 = __shfl(sA, k + q);
            float p0 = __shfl(pA, k + q);
            int   s1 = __shfl(sA, k + 4 + q);
            float p1 = __shfl(pA, k + 4 + q);
            const float4 hv0 = *(const float4*)&h[(size_t)s0 * HID + ch];
            const float4 hv1 = *(const float4*)&h[(size_t)s1 * HID + ch];
            acc.x  = fmaf(p0, hv0.x, acc.x);
            acc.y  = fmaf(p0, hv0.y, acc.y);
            acc.z  = fmaf(p0, hv0.z, acc.z);
            acc.w  = fmaf(p0, hv0.w, acc.w);
            acc2.x = fmaf(p1, hv1.x, acc2.x);
            acc2.y = fmaf(p1, hv1.y, acc2.y);
            acc2.z = fmaf(p1, hv1.z, acc2.z);
            acc2.w = fmaf(p1, hv1.w, acc2.w);
        }
        for (; k < mainN; k += 4) {
            int   s = __shfl(sA, k + q);
            float p = __shfl(pA, k + q);
            const float4 hv = *(const float4*)&h[(size_t)s * HID + ch];
            acc.x = fmaf(p, hv.x, acc.x);
            acc.y = fmaf(p, hv.y, acc.y);
            acc.z = fmaf(p, hv.z, acc.z);
            acc.w = fmaf(p, hv.w, acc.w);
        }
        acc.x += acc2.x; acc.y += acc2.y; acc.z += acc2.z; acc.w += acc2.w;

        // rare tail: deg > 64
        float sumX = 0.f;
        for (int kk0 = k0 + 64; kk0 < k1; kk0 += 4) {
            int kk = kk0 + q;
            bool valid = (kk < k1);
            int s = valid ? sorted_src[kk] : d;
            float e = al_s[s] + ald;
            e = (e > 0.f) ? e : LR_ATT * e;
            float ex = valid ? __expf(e - m) : 0.f;
            const float4 hv = *(const float4*)&h[(size_t)s * HID + ch];
            acc.x = fmaf(ex, hv.x, acc.x);
            acc.y = fmaf(ex, hv.y, acc.y);
            acc.z = fmaf(ex, hv.z, acc.z);
            acc.w = fmaf(ex, hv.w, acc.w);
            sumX += ex;
        }

        // ---- combine the four quarters ----
        #pragma unroll
        for (int off = 16; off <= 32; off <<= 1) {
            acc.x += __shfl_xor(acc.x, off);
            acc.y += __shfl_xor(acc.y, off);
            acc.z += __shfl_xor(acc.z, off);
            acc.w += __shfl_xor(acc.w, off);
            sumX  += __shfl_xor(sumX, off);
        }
        sum += sumX;

        float inv = 1.f / sum;
        float4 v;
        v.x = fmaf(acc.x, inv, bc.x); v.y = fmaf(acc.y, inv, bc.y);
        v.z = fmaf(acc.z, inv, bc.z); v.w = fmaf(acc.w, inv, bc.w);
        v.x = (v.x > 0.f) ? v.x : LR_ACT * v.x;
        v.y = (v.y > 0.f) ? v.y : LR_ACT * v.y;
        v.z = (v.z > 0.f) ? v.z : LR_ACT * v.z;
        v.w = (v.w > 0.f) ? v.w : LR_ACT * v.w;

        if (!FUSE_HEAD) {
            if (lane < 16) *(float4*)&hout[(size_t)d * HID + ch] = v;
        } else {
            float t = v.x * wc.x + v.y * wc.y + v.z * wc.z + v.w * wc.w;
            #pragma unroll
            for (int off = 8; off; off >>= 1) t += __shfl_xor(t, off);
            if (lane == 0) out[d] = t + bout[0];
        }
    }
}

extern "C" void kernel_launch(void* const* d_in, const int* in_sizes, int n_in,
                              void* d_out, int out_size, void* d_ws, size_t ws_size,
                              hipStream_t stream)
{
    const float* x      = (const float*)d_in[0];
    const int*   ei     = (const int*)  d_in[1];
    const float* W1     = (const float*)d_in[2];
    const float* a_src1 = (const float*)d_in[3];
    const float* a_dst1 = (const float*)d_in[4];
    const float* b1     = (const float*)d_in[5];
    const float* W2     = (const float*)d_in[6];
    const float* a_src2 = (const float*)d_in[7];
    const float* a_dst2 = (const float*)d_in[8];
    const float* b2     = (const float*)d_in[9];
    const float* W3     = (const float*)d_in[10];
    const float* a_src3 = (const float*)d_in[11];
    const float* a_dst3 = (const float*)d_in[12];
    const float* b3     = (const float*)d_in[13];
    const float* W_out  = (const float*)d_in[14];
    const float* b_out  = (const float*)d_in[15];
    float* out = (float*)d_out;

    const int n = out_size;           // 50000 nodes
    const int E = in_sizes[1] / 2;    // 1.6M edges

    const int* src = ei;
    const int* dst = ei + E;

    // workspace layout
    float* ws   = (float*)d_ws;
    float* hA   = ws;                        // n*64
    float* hB   = hA + (size_t)n * HID;      // n*64
    float* al_s = hB + (size_t)n * HID;      // n
    float* al_d = al_s + n;                  // n
    int* counts     = (int*)(al_d + n);      // n
    int* offsets    = counts + n;            // n+1
    int* part       = offsets + (n + 1);     // 256
    int* rank       = part + 256;            // E
    int* sorted_src = rank + E;              // E

    dim3 blk(256);
    const int gemm_grid = (n + 15) / 16;           // 16 nodes/block, exact cover
    const int edge_grid = 4096;
    const int node_grid = (n + 3) / 4;             // 4 waves/block, 1 wave/node
    const int nPart     = (n + SCHUNK - 1) / SCHUNK;  // 49 scan blocks

    // ---- CSR build (graph is layer-invariant) ----
    (void)hipMemsetAsync(counts, 0, (size_t)n * sizeof(int), stream);
    count_rank_kernel<<<edge_grid, blk, 0, stream>>>(dst, counts, rank, E);
    scan_reduce_kernel<<<nPart, blk, 0, stream>>>(counts, part, n);
    scan_top_kernel<<<1, blk, 0, stream>>>(part, nPart, offsets, n);
    scan_apply_kernel<<<nPart, blk, 0, stream>>>(counts, part, offsets, n);
    scatter_write_kernel<<<edge_grid, blk, 0, stream>>>(src, dst, rank, offsets,
        sorted_src, E);

    // ---- layer 1 (K = 128) ----
    gemm_att_lds4_kernel<128><<<gemm_grid, blk, 0, stream>>>(x, W1, a_src1, a_dst1,
        hA, al_s, al_d, n);
    node_agg_kernel<false><<<node_grid, blk, 0, stream>>>(offsets, sorted_src,
        al_s, al_d, hA, b1, hB, nullptr, nullptr, nullptr, n);

    // ---- layer 2 (K = 64) ----
    gemm_att_lds4_kernel<64><<<gemm_grid, blk, 0, stream>>>(hB, W2, a_src2, a_dst2,
        hA, al_s, al_d, n);
    node_agg_kernel<false><<<node_grid, blk, 0, stream>>>(offsets, sorted_src,
        al_s, al_d, hA, b2, hB, nullptr, nullptr, nullptr, n);

    // ---- layer 3 (K = 64) + fused output head ----
    gemm_att_lds4_kernel<64><<<gemm_grid, blk, 0, stream>>>(hB, W3, a_src3, a_dst3,
        hA, al_s, al_d, n);
    node_agg_kernel<true><<<node_grid, blk, 0, stream>>>(offsets, sorted_src,
        al_s, al_d, hA, b3, nullptr, W_out, b_out, out, n);
}

// Round 24
// 321.379 us; speedup vs baseline: 1.3720x; 1.2769x over previous
//
#include <hip/hip_runtime.h>
#include <math.h>

#define HID 64
#define LR_ATT 0.2f
#define LR_ACT 0.01f
#define SCHUNK 1024   // elements per scan block

// ---------------- CSR build (once per call; graph shared by all 3 layers) ----------------

// Pass 1: per-dst count AND within-bucket rank in one atomic.
__global__ __launch_bounds__(256) void count_rank_kernel(
    const int* __restrict__ dst, int* __restrict__ counts,
    int* __restrict__ rank, int E)
{
    int i = blockIdx.x * blockDim.x + threadIdx.x;
    int stride = gridDim.x * blockDim.x;
    for (; i < E; i += stride)
        rank[i] = atomicAdd(&counts[dst[i]], 1);
}

// Hierarchical scan (n up to 256*SCHUNK): reduce -> top scan -> apply.
__global__ __launch_bounds__(256) void scan_reduce_kernel(
    const int* __restrict__ counts, int* __restrict__ part, int n)
{
    __shared__ int sdata[256];
    const int b = blockIdx.x, t = threadIdx.x;
    const int base = b * SCHUNK;
    int sum = 0;
    for (int i = base + t; i < n && i < base + SCHUNK; i += 256) sum += counts[i];
    sdata[t] = sum;
    __syncthreads();
    for (int off = 128; off; off >>= 1) {
        if (t < off) sdata[t] += sdata[t + off];
        __syncthreads();
    }
    if (t == 0) part[b] = sdata[0];
}

__global__ __launch_bounds__(256) void scan_top_kernel(
    int* __restrict__ part, int nPart, int* __restrict__ offsets, int n)
{
    __shared__ int sdata[256];
    const int t = threadIdx.x;
    int v = (t < nPart) ? part[t] : 0;
    sdata[t] = v;
    __syncthreads();
    for (int off = 1; off < 256; off <<= 1) {
        int u = (t >= off) ? sdata[t - off] : 0;
        __syncthreads();
        sdata[t] += u;
        __syncthreads();
    }
    if (t < nPart) part[t] = sdata[t] - v;     // exclusive block prefix
    if (t == 255) offsets[n] = sdata[255];     // total == E
}

__global__ __launch_bounds__(256) void scan_apply_kernel(
    const int* __restrict__ counts, const int* __restrict__ part,
    int* __restrict__ offsets, int n)
{
    __shared__ int sdata[256];
    const int b = blockIdx.x, t = threadIdx.x;
    const int i0 = b * SCHUNK + t * 4;
    int c[4];
    int s = 0;
    #pragma unroll
    for (int j = 0; j < 4; ++j) {
        int i = i0 + j;
        c[j] = (i < n) ? counts[i] : 0;
        s += c[j];
    }
    sdata[t] = s;
    __syncthreads();
    for (int off = 1; off < 256; off <<= 1) {
        int u = (t >= off) ? sdata[t - off] : 0;
        __syncthreads();
        sdata[t] += u;
        __syncthreads();
    }
    int run = part[b] + sdata[t] - s;          // exclusive base for this thread
    #pragma unroll
    for (int j = 0; j < 4; ++j) {
        int i = i0 + j;
        if (i < n) offsets[i] = run;
        run += c[j];
    }
}

// Pass 2: independent random writes (full MLP, no atomic dependency).
__global__ __launch_bounds__(256) void scatter_write_kernel(
    const int* __restrict__ src, const int* __restrict__ dst,
    const int* __restrict__ rank, const int* __restrict__ offsets,
    int* __restrict__ sorted_src, int E)
{
    int i = blockIdx.x * blockDim.x + threadIdx.x;
    int stride = gridDim.x * blockDim.x;
    for (; i < E; i += stride)
        sorted_src[offsets[dst[i]] + rank[i]] = src[i];
}

// ---------------- per-layer kernels ----------------

// Block-tiled GEMM: block = TR nodes x 64 channels. x-tile staged COALESCED
// into xs[TR][K+4] (pad 4 -> read bank = 4*row+k, conflict-free), W staged
// into ws. Thread computes NR nodes x 4 channels; per k: 1 ds_read_b128 (W)
// + NR b32 broadcasts (x) + 4*NR fma. Attention partials reduced over the
// 16-lane channel group via shfl_xor.
template<int K>
__global__ __launch_bounds__(256) void gemm_tile_kernel(
    const float* __restrict__ hin, const float* __restrict__ W,
    const float* __restrict__ a_src, const float* __restrict__ a_dst,
    float* __restrict__ hout, float* __restrict__ al_s, float* __restrict__ al_d,
    int n_nodes)
{
    constexpr int TR = (K > 64) ? 32 : 64;   // tile rows (LDS budget)
    constexpr int NR = TR / 16;              // nodes per thread
    constexpr int KP = K + 4;                // padded row stride (16B-aligned)
    constexpr int NK4 = K / 4;

    __shared__ float ws[K * HID];
    __shared__ float xs[TR * KP];

    const int t = threadIdx.x;
    const int base = blockIdx.x * TR;

    for (int i = t; i < K * HID; i += 256) ws[i] = W[i];

    for (int f = t; f < TR * NK4; f += 256) {
        int row = f / NK4, k4 = f % NK4;
        if (base + row < n_nodes)
            *(float4*)&xs[row * KP + k4 * 4] =
                *(const float4*)(hin + (size_t)(base + row) * K + k4 * 4);
    }
    __syncthreads();

    const int ch0 = (t & 15) * 4;
    const int ng  = (t >> 4) * NR;

    float4 acc[NR];
    #pragma unroll
    for (int j = 0; j < NR; ++j) acc[j] = float4{0.f, 0.f, 0.f, 0.f};

    #pragma unroll 4
    for (int k = 0; k < K; ++k) {
        const float4 wv = *(const float4*)&ws[k * HID + ch0];
        #pragma unroll
        for (int j = 0; j < NR; ++j) {
            const float xv = xs[(ng + j) * KP + k];
            acc[j].x = fmaf(xv, wv.x, acc[j].x);
            acc[j].y = fmaf(xv, wv.y, acc[j].y);
            acc[j].z = fmaf(xv, wv.z, acc[j].z);
            acc[j].w = fmaf(xv, wv.w, acc[j].w);
        }
    }

    const float4 as4 = *(const float4*)&a_src[ch0];
    const float4 ad4 = *(const float4*)&a_dst[ch0];

    #pragma unroll
    for (int j = 0; j < NR; ++j) {
        const int row = base + ng + j;
        if (row < n_nodes) {
            *(float4*)&hout[(size_t)row * HID + ch0] = acc[j];
            float ps = acc[j].x * as4.x + acc[j].y * as4.y
                     + acc[j].z * as4.z + acc[j].w * as4.w;
            float pd = acc[j].x * ad4.x + acc[j].y * ad4.y
                     + acc[j].z * ad4.z + acc[j].w * ad4.w;
            #pragma unroll
            for (int off = 8; off; off >>= 1) {
                ps += __shfl_xor(ps, off);
                pd += __shfl_xor(pd, off);
            }
            if ((t & 15) == 0) {
                al_s[row] = ps;
                al_d[row] = pd;
            }
        }
    }
}

// One wave per dst node. Phase 1: lane ℓ preloads edge ℓ's src + logit
// (coalesced), wave-max, p = exp(e-m) per lane, denominator via ONE wave
// reduce. Phase 2: quarter-wave per edge, TWO independent gather+fma
// streams (8 edges/iteration) to double memory-level parallelism.
template<bool FUSE_HEAD>
__global__ __launch_bounds__(256) void node_agg_kernel(
    const int* __restrict__ offsets, const int* __restrict__ sorted_src,
    const float* __restrict__ al_s, const float* __restrict__ al_d,
    const float* __restrict__ h, const float* __restrict__ b,
    float* __restrict__ hout,
    const float* __restrict__ Wout, const float* __restrict__ bout,
    float* __restrict__ out, int n_nodes)
{
    const int lane = threadIdx.x & 63;
    const int q    = lane >> 4;        // quarter: which edge of the 4
    const int ch   = (lane & 15) * 4;  // float4 channel quad
    const int wib  = threadIdx.x >> 6;
    const int wpb  = blockDim.x >> 6;
    int wid = blockIdx.x * wpb + wib;
    int nw  = gridDim.x * wpb;

    const float4 bc = *(const float4*)&b[ch];
    const float4 wc = FUSE_HEAD ? *(const float4*)&Wout[ch] : float4{0.f,0.f,0.f,0.f};

    for (int d = wid; d < n_nodes; d += nw) {
        const float ald = al_d[d];
        float e0 = al_s[d] + ald;           // self-loop logit
        e0 = (e0 > 0.f) ? e0 : LR_ATT * e0;

        const int k0  = offsets[d];
        const int k1  = offsets[d + 1];
        const int deg = k1 - k0;

        // ---- phase 1: preload + max + softmax weights + denominator ----
        int   sA = d;
        float eA = __int_as_float(0xff800000);  // -inf
        if (lane < deg) {
            sA = sorted_src[k0 + lane];
            float e = al_s[sA] + ald;
            eA = (e > 0.f) ? e : LR_ATT * e;
        }
        float lm = fmaxf(e0, eA);
        for (int k = k0 + 64 + lane; k < k1; k += 64) {  // rare: deg > 64
            int s = sorted_src[k];
            float e = al_s[s] + ald;
            e = (e > 0.f) ? e : LR_ATT * e;
            lm = fmaxf(lm, e);
        }
        #pragma unroll
        for (int off = 32; off; off >>= 1)
            lm = fmaxf(lm, __shfl_xor(lm, off));
        const float m = lm;

        const float ex0 = __expf(e0 - m);
        float pA = (lane < deg) ? __expf(eA - m) : 0.f;
        float ssum = pA;
        #pragma unroll
        for (int off = 32; off; off >>= 1) ssum += __shfl_xor(ssum, off);
        float sum = ssum + ex0;                 // wave-uniform denominator

        // ---- phase 2: gather-accumulate, 2 streams x 4 edges ----
        const float4 hd = *(const float4*)&h[(size_t)d * HID + ch];
        float exq = (q == 0) ? ex0 : 0.f;       // self-loop in quarter 0
        float4 acc, acc2;
        acc.x  = exq * hd.x; acc.y  = exq * hd.y;
        acc.z  = exq * hd.z; acc.w  = exq * hd.w;
        acc2.x = 0.f; acc2.y = 0.f; acc2.z = 0.f; acc2.w = 0.f;

        const int mainN = min(deg, 64);
        int k = 0;
        for (; k + 8 <= mainN; k += 8) {
            int   s0 = __shfl(sA, k + q);
            float p0 = __shfl(pA, k + q);
            int   s1 = __shfl(sA, k + 4 + q);
            float p1 = __shfl(pA, k + 4 + q);
            const float4 hv0 = *(const float4*)&h[(size_t)s0 * HID + ch];
            const float4 hv1 = *(const float4*)&h[(size_t)s1 * HID + ch];
            acc.x  = fmaf(p0, hv0.x, acc.x);
            acc.y  = fmaf(p0, hv0.y, acc.y);
            acc.z  = fmaf(p0, hv0.z, acc.z);
            acc.w  = fmaf(p0, hv0.w, acc.w);
            acc2.x = fmaf(p1, hv1.x, acc2.x);
            acc2.y = fmaf(p1, hv1.y, acc2.y);
            acc2.z = fmaf(p1, hv1.z, acc2.z);
            acc2.w = fmaf(p1, hv1.w, acc2.w);
        }
        for (; k < mainN; k += 4) {
            int   s = __shfl(sA, k + q);
            float p = __shfl(pA, k + q);
            const float4 hv = *(const float4*)&h[(size_t)s * HID + ch];
            acc.x = fmaf(p, hv.x, acc.x);
            acc.y = fmaf(p, hv.y, acc.y);
            acc.z = fmaf(p, hv.z, acc.z);
            acc.w = fmaf(p, hv.w, acc.w);
        }
        acc.x += acc2.x; acc.y += acc2.y; acc.z += acc2.z; acc.w += acc2.w;

        // rare tail: deg > 64
        float sumX = 0.f;
        for (int kk0 = k0 + 64; kk0 < k1; kk0 += 4) {
            int kk = kk0 + q;
            bool valid = (kk < k1);
            int s = valid ? sorted_src[kk] : d;
            float e = al_s[s] + ald;
            e = (e > 0.f) ? e : LR_ATT * e;
            float ex = valid ? __expf(e - m) : 0.f;
            const float4 hv = *(const float4*)&h[(size_t)s * HID + ch];
            acc.x = fmaf(ex, hv.x, acc.x);
            acc.y = fmaf(ex, hv.y, acc.y);
            acc.z = fmaf(ex, hv.z, acc.z);
            acc.w = fmaf(ex, hv.w, acc.w);
            sumX += ex;
        }

        // ---- combine the four quarters ----
        #pragma unroll
        for (int off = 16; off <= 32; off <<= 1) {
            acc.x += __shfl_xor(acc.x, off);
            acc.y += __shfl_xor(acc.y, off);
            acc.z += __shfl_xor(acc.z, off);
            acc.w += __shfl_xor(acc.w, off);
            sumX  += __shfl_xor(sumX, off);
        }
        sum += sumX;

        float inv = 1.f / sum;
        float4 v;
        v.x = fmaf(acc.x, inv, bc.x); v.y = fmaf(acc.y, inv, bc.y);
        v.z = fmaf(acc.z, inv, bc.z); v.w = fmaf(acc.w, inv, bc.w);
        v.x = (v.x > 0.f) ? v.x : LR_ACT * v.x;
        v.y = (v.y > 0.f) ? v.y : LR_ACT * v.y;
        v.z = (v.z > 0.f) ? v.z : LR_ACT * v.z;
        v.w = (v.w > 0.f) ? v.w : LR_ACT * v.w;

        if (!FUSE_HEAD) {
            if (lane < 16) *(float4*)&hout[(size_t)d * HID + ch] = v;
        } else {
            float t = v.x * wc.x + v.y * wc.y + v.z * wc.z + v.w * wc.w;
            #pragma unroll
            for (int off = 8; off; off >>= 1) t += __shfl_xor(t, off);
            if (lane == 0) out[d] = t + bout[0];
        }
    }
}

extern "C" void kernel_launch(void* const* d_in, const int* in_sizes, int n_in,
                              void* d_out, int out_size, void* d_ws, size_t ws_size,
                              hipStream_t stream)
{
    const float* x      = (const float*)d_in[0];
    const int*   ei     = (const int*)  d_in[1];
    const float* W1     = (const float*)d_in[2];
    const float* a_src1 = (const float*)d_in[3];
    const float* a_dst1 = (const float*)d_in[4];
    const float* b1     = (const float*)d_in[5];
    const float* W2     = (const float*)d_in[6];
    const float* a_src2 = (const float*)d_in[7];
    const float* a_dst2 = (const float*)d_in[8];
    const float* b2     = (const float*)d_in[9];
    const float* W3     = (const float*)d_in[10];
    const float* a_src3 = (const float*)d_in[11];
    const float* a_dst3 = (const float*)d_in[12];
    const float* b3     = (const float*)d_in[13];
    const float* W_out  = (const float*)d_in[14];
    const float* b_out  = (const float*)d_in[15];
    float* out = (float*)d_out;

    const int n = out_size;           // 50000 nodes
    const int E = in_sizes[1] / 2;    // 1.6M edges

    const int* src = ei;
    const int* dst = ei + E;

    // workspace layout
    float* ws   = (float*)d_ws;
    float* hA   = ws;                        // n*64
    float* hB   = hA + (size_t)n * HID;      // n*64
    float* al_s = hB + (size_t)n * HID;      // n
    float* al_d = al_s + n;                  // n
    int* counts     = (int*)(al_d + n);      // n
    int* offsets    = counts + n;            // n+1
    int* part       = offsets + (n + 1);     // 256
    int* rank       = part + 256;            // E
    int* sorted_src = rank + E;              // E

    dim3 blk(256);
    const int edge_grid  = 4096;
    const int node_grid  = (n + 3) / 4;            // 4 waves/block, 1 wave/node
    const int gemm1_grid = (n + 31) / 32;          // 32-node tiles (K=128)
    const int gemm2_grid = (n + 63) / 64;          // 64-node tiles (K=64)
    const int nPart      = (n + SCHUNK - 1) / SCHUNK;  // 49 scan blocks

    // ---- CSR build (graph is layer-invariant) ----
    (void)hipMemsetAsync(counts, 0, (size_t)n * sizeof(int), stream);
    count_rank_kernel<<<edge_grid, blk, 0, stream>>>(dst, counts, rank, E);
    scan_reduce_kernel<<<nPart, blk, 0, stream>>>(counts, part, n);
    scan_top_kernel<<<1, blk, 0, stream>>>(part, nPart, offsets, n);
    scan_apply_kernel<<<nPart, blk, 0, stream>>>(counts, part, offsets, n);
    scatter_write_kernel<<<edge_grid, blk, 0, stream>>>(src, dst, rank, offsets,
        sorted_src, E);

    // ---- layer 1 (K = 128) ----
    gemm_tile_kernel<128><<<gemm1_grid, blk, 0, stream>>>(x, W1, a_src1, a_dst1,
        hA, al_s, al_d, n);
    node_agg_kernel<false><<<node_grid, blk, 0, stream>>>(offsets, sorted_src,
        al_s, al_d, hA, b1, hB, nullptr, nullptr, nullptr, n);

    // ---- layer 2 (K = 64) ----
    gemm_tile_kernel<64><<<gemm2_grid, blk, 0, stream>>>(hB, W2, a_src2, a_dst2,
        hA, al_s, al_d, n);
    node_agg_kernel<false><<<node_grid, blk, 0, stream>>>(offsets, sorted_src,
        al_s, al_d, hA, b2, hB, nullptr, nullptr, nullptr, n);

    // ---- layer 3 (K = 64) + fused output head ----
    gemm_tile_kernel<64><<<gemm2_grid, blk, 0, stream>>>(hB, W3, a_src3, a_dst3,
        hA, al_s, al_d, n);
    node_agg_kernel<true><<<node_grid, blk, 0, stream>>>(offsets, sorted_src,
        al_s, al_d, hA, b3, nullptr, W_out, b_out, out, n);
}

// Round 31
// 289.123 us; speedup vs baseline: 1.5251x; 1.1116x over previous
//
#include <hip/hip_runtime.h>
#include <math.h>

#define HID 64
#define LR_ATT 0.2f
#define LR_ACT 0.01f
#define BSHIFT 8          // bucket = dst >> 8 (256 dsts per bucket)
#define TILE 2048         // edges per bucket_scatter tile

// ---------------- CSR build via 2-level LDS bucket sort (no per-edge global atomics) ----------------

// Pass A: global bucket histogram, LDS-aggregated (one global atomic per block x bucket).
__global__ __launch_bounds__(256) void bucket_hist_kernel(
    const int* __restrict__ dst, int* __restrict__ bucket_counts, int E, int NB)
{
    __shared__ int h[256];
    h[threadIdx.x] = 0;
    __syncthreads();
    int i = blockIdx.x * blockDim.x + threadIdx.x;
    int stride = gridDim.x * blockDim.x;
    for (; i < E; i += stride) atomicAdd(&h[dst[i] >> BSHIFT], 1);
    __syncthreads();
    if (threadIdx.x < NB && h[threadIdx.x])
        atomicAdd(&bucket_counts[threadIdx.x], h[threadIdx.x]);
}

// Scan NB (<=256) bucket counts -> bucket_off[NB+1]; init cursor; offsets[n]=E.
__global__ __launch_bounds__(256) void bucket_scan_kernel(
    const int* __restrict__ bucket_counts, int* __restrict__ bucket_off,
    int* __restrict__ cursor, int* __restrict__ offsets, int NB, int n, int E)
{
    __shared__ int sd[256];
    const int t = threadIdx.x;
    int v = (t < NB) ? bucket_counts[t] : 0;
    sd[t] = v;
    __syncthreads();
    for (int off = 1; off < 256; off <<= 1) {
        int u = (t >= off) ? sd[t - off] : 0;
        __syncthreads();
        sd[t] += u;
        __syncthreads();
    }
    int excl = sd[t] - v;
    if (t < NB) { bucket_off[t] = excl; cursor[t] = excl; }
    if (t == 255) { bucket_off[NB] = sd[255]; offsets[n] = E; }
}

// Pass B: scatter edges into bucket regions. Per tile: LDS rank+scan, one
// reservation atomic per bucket, LDS reorder, then near-coalesced u64 writes.
__global__ __launch_bounds__(256) void bucket_scatter_kernel(
    const int* __restrict__ src, const int* __restrict__ dst,
    int* __restrict__ cursor, unsigned long long* __restrict__ bucketed,
    int E, int NB)
{
    constexpr int EPT = TILE / 256;  // edges per thread
    __shared__ int cnt[256], lo[256], gb[256];
    __shared__ unsigned long long stg[TILE];

    const int t = threadIdx.x;
    const int base = blockIdx.x * TILE;
    const int tcount = min(TILE, E - base);

    cnt[t] = 0;
    __syncthreads();

    unsigned long long e[EPT];
    int r[EPT], bb[EPT];
    #pragma unroll
    for (int j = 0; j < EPT; ++j) {
        int idx = base + j * 256 + t;
        if (idx < E) {
            int d = dst[idx], s = src[idx];
            e[j]  = ((unsigned long long)(unsigned)d << 32) | (unsigned)s;
            bb[j] = d >> BSHIFT;
            r[j]  = atomicAdd(&cnt[bb[j]], 1);
        } else {
            bb[j] = -1;
        }
    }
    __syncthreads();

    const int v = cnt[t];
    lo[t] = v;
    __syncthreads();
    for (int off = 1; off < 256; off <<= 1) {
        int u = (t >= off) ? lo[t - off] : 0;
        __syncthreads();
        lo[t] += u;
        __syncthreads();
    }
    const int excl = lo[t] - v;
    __syncthreads();
    lo[t] = excl;
    if (t < NB) gb[t] = atomicAdd(&cursor[t], v);
    __syncthreads();

    #pragma unroll
    for (int j = 0; j < EPT; ++j)
        if (bb[j] >= 0) stg[lo[bb[j]] + r[j]] = e[j];
    __syncthreads();

    for (int j = t; j < tcount; j += 256) {
        unsigned long long ev = stg[j];
        int b = (int)(ev >> 32) >> BSHIFT;
        bucketed[gb[b] + (j - lo[b])] = ev;
    }
}

// Pass C: one block per bucket -- exact within-bucket sort by dst; emits
// sorted_src and per-dst offsets. All LDS atomics; coalesced-run writes.
__global__ __launch_bounds__(256) void bucket_sort_kernel(
    const unsigned long long* __restrict__ bucketed,
    const int* __restrict__ bucket_off,
    int* __restrict__ sorted_src, int* __restrict__ offsets, int n)
{
    __shared__ int dcnt[256], loff[256], cur[256];
    const int b = blockIdx.x, t = threadIdx.x;
    const int bo = bucket_off[b], bo1 = bucket_off[b + 1];

    dcnt[t] = 0;
    __syncthreads();
    for (int j = bo + t; j < bo1; j += 256)
        atomicAdd(&dcnt[(int)(bucketed[j] >> 32) & 255], 1);
    __syncthreads();

    const int v = dcnt[t];
    loff[t] = v;
    __syncthreads();
    for (int off = 1; off < 256; off <<= 1) {
        int u = (t >= off) ? loff[t - off] : 0;
        __syncthreads();
        loff[t] += u;
        __syncthreads();
    }
    const int excl = loff[t] - v;
    __syncthreads();
    loff[t] = excl;
    cur[t]  = excl;
    __syncthreads();

    const int d_global = (b << BSHIFT) + t;
    if (d_global < n) offsets[d_global] = bo + excl;

    for (int j = bo + t; j < bo1; j += 256) {
        unsigned long long ev = bucketed[j];
        int d = (int)(ev >> 32);
        int slot = atomicAdd(&cur[d & 255], 1);
        sorted_src[bo + slot] = (int)(ev & 0xffffffffu);
    }
}

// ---------------- per-layer kernels ----------------

// Block-tiled GEMM: block = TR nodes x 64 channels (see r24 notes).
template<int K>
__global__ __launch_bounds__(256) void gemm_tile_kernel(
    const float* __restrict__ hin, const float* __restrict__ W,
    const float* __restrict__ a_src, const float* __restrict__ a_dst,
    float* __restrict__ hout, float* __restrict__ al_s, float* __restrict__ al_d,
    int n_nodes)
{
    constexpr int TR = (K > 64) ? 32 : 64;
    constexpr int NR = TR / 16;
    constexpr int KP = K + 4;
    constexpr int NK4 = K / 4;

    __shared__ float ws[K * HID];
    __shared__ float xs[TR * KP];

    const int t = threadIdx.x;
    const int base = blockIdx.x * TR;

    for (int i = t; i < K * HID; i += 256) ws[i] = W[i];

    for (int f = t; f < TR * NK4; f += 256) {
        int row = f / NK4, k4 = f % NK4;
        if (base + row < n_nodes)
            *(float4*)&xs[row * KP + k4 * 4] =
                *(const float4*)(hin + (size_t)(base + row) * K + k4 * 4);
    }
    __syncthreads();

    const int ch0 = (t & 15) * 4;
    const int ng  = (t >> 4) * NR;

    float4 acc[NR];
    #pragma unroll
    for (int j = 0; j < NR; ++j) acc[j] = float4{0.f, 0.f, 0.f, 0.f};

    #pragma unroll 4
    for (int k = 0; k < K; ++k) {
        const float4 wv = *(const float4*)&ws[k * HID + ch0];
        #pragma unroll
        for (int j = 0; j < NR; ++j) {
            const float xv = xs[(ng + j) * KP + k];
            acc[j].x = fmaf(xv, wv.x, acc[j].x);
            acc[j].y = fmaf(xv, wv.y, acc[j].y);
            acc[j].z = fmaf(xv, wv.z, acc[j].z);
            acc[j].w = fmaf(xv, wv.w, acc[j].w);
        }
    }

    const float4 as4 = *(const float4*)&a_src[ch0];
    const float4 ad4 = *(const float4*)&a_dst[ch0];

    #pragma unroll
    for (int j = 0; j < NR; ++j) {
        const int row = base + ng + j;
        if (row < n_nodes) {
            *(float4*)&hout[(size_t)row * HID + ch0] = acc[j];
            float ps = acc[j].x * as4.x + acc[j].y * as4.y
                     + acc[j].z * as4.z + acc[j].w * as4.w;
            float pd = acc[j].x * ad4.x + acc[j].y * ad4.y
                     + acc[j].z * ad4.z + acc[j].w * ad4.w;
            #pragma unroll
            for (int off = 8; off; off >>= 1) {
                ps += __shfl_xor(ps, off);
                pd += __shfl_xor(pd, off);
            }
            if ((t & 15) == 0) {
                al_s[row] = ps;
                al_d[row] = pd;
            }
        }
    }
}

// One wave per dst node; precomputed softmax, 2-stream float4 gathers.
template<bool FUSE_HEAD>
__global__ __launch_bounds__(256) void node_agg_kernel(
    const int* __restrict__ offsets, const int* __restrict__ sorted_src,
    const float* __restrict__ al_s, const float* __restrict__ al_d,
    const float* __restrict__ h, const float* __restrict__ b,
    float* __restrict__ hout,
    const float* __restrict__ Wout, const float* __restrict__ bout,
    float* __restrict__ out, int n_nodes)
{
    const int lane = threadIdx.x & 63;
    const int q    = lane >> 4;
    const int ch   = (lane & 15) * 4;
    const int wib  = threadIdx.x >> 6;
    const int wpb  = blockDim.x >> 6;
    int wid = blockIdx.x * wpb + wib;
    int nw  = gridDim.x * wpb;

    const float4 bc = *(const float4*)&b[ch];
    const float4 wc = FUSE_HEAD ? *(const float4*)&Wout[ch] : float4{0.f,0.f,0.f,0.f};

    for (int d = wid; d < n_nodes; d += nw) {
        const float ald = al_d[d];
        float e0 = al_s[d] + ald;
        e0 = (e0 > 0.f) ? e0 : LR_ATT * e0;

        const int k0  = offsets[d];
        const int k1  = offsets[d + 1];
        const int deg = k1 - k0;

        int   sA = d;
        float eA = __int_as_float(0xff800000);
        if (lane < deg) {
            sA = sorted_src[k0 + lane];
            float e = al_s[sA] + ald;
            eA = (e > 0.f) ? e : LR_ATT * e;
        }
        float lm = fmaxf(e0, eA);
        for (int k = k0 + 64 + lane; k < k1; k += 64) {
            int s = sorted_src[k];
            float e = al_s[s] + ald;
            e = (e > 0.f) ? e : LR_ATT * e;
            lm = fmaxf(lm, e);
        }
        #pragma unroll
        for (int off = 32; off; off >>= 1)
            lm = fmaxf(lm, __shfl_xor(lm, off));
        const float m = lm;

        const float ex0 = __expf(e0 - m);
        float pA = (lane < deg) ? __expf(eA - m) : 0.f;
        float ssum = pA;
        #pragma unroll
        for (int off = 32; off; off >>= 1) ssum += __shfl_xor(ssum, off);
        float sum = ssum + ex0;

        const float4 hd = *(const float4*)&h[(size_t)d * HID + ch];
        float exq = (q == 0) ? ex0 : 0.f;
        float4 acc, acc2;
        acc.x  = exq * hd.x; acc.y  = exq * hd.y;
        acc.z  = exq * hd.z; acc.w  = exq * hd.w;
        acc2.x = 0.f; acc2.y = 0.f; acc2.z = 0.f; acc2.w = 0.f;

        const int mainN = min(deg, 64);
        int k = 0;
        for (; k + 8 <= mainN; k += 8) {
            int   s0 = __shfl(sA, k + q);
            float p0 = __shfl(pA, k + q);
            int   s1 = __shfl(sA, k + 4 + q);
            float p1 = __shfl(pA, k + 4 + q);
            const float4 hv0 = *(const float4*)&h[(size_t)s0 * HID + ch];
            const float4 hv1 = *(const float4*)&h[(size_t)s1 * HID + ch];
            acc.x  = fmaf(p0, hv0.x, acc.x);
            acc.y  = fmaf(p0, hv0.y, acc.y);
            acc.z  = fmaf(p0, hv0.z, acc.z);
            acc.w  = fmaf(p0, hv0.w, acc.w);
            acc2.x = fmaf(p1, hv1.x, acc2.x);
            acc2.y = fmaf(p1, hv1.y, acc2.y);
            acc2.z = fmaf(p1, hv1.z, acc2.z);
            acc2.w = fmaf(p1, hv1.w, acc2.w);
        }
        for (; k < mainN; k += 4) {
            int   s = __shfl(sA, k + q);
            float p = __shfl(pA, k + q);
            const float4 hv = *(const float4*)&h[(size_t)s * HID + ch];
            acc.x = fmaf(p, hv.x, acc.x);
            acc.y = fmaf(p, hv.y, acc.y);
            acc.z = fmaf(p, hv.z, acc.z);
            acc.w = fmaf(p, hv.w, acc.w);
        }
        acc.x += acc2.x; acc.y += acc2.y; acc.z += acc2.z; acc.w += acc2.w;

        float sumX = 0.f;
        for (int kk0 = k0 + 64; kk0 < k1; kk0 += 4) {
            int kk = kk0 + q;
            bool valid = (kk < k1);
            int s = valid ? sorted_src[kk] : d;
            float e = al_s[s] + ald;
            e = (e > 0.f) ? e : LR_ATT * e;
            float ex = valid ? __expf(e - m) : 0.f;
            const float4 hv = *(const float4*)&h[(size_t)s * HID + ch];
            acc.x = fmaf(ex, hv.x, acc.x);
            acc.y = fmaf(ex, hv.y, acc.y);
            acc.z = fmaf(ex, hv.z, acc.z);
            acc.w = fmaf(ex, hv.w, acc.w);
            sumX += ex;
        }

        #pragma unroll
        for (int off = 16; off <= 32; off <<= 1) {
            acc.x += __shfl_xor(acc.x, off);
            acc.y += __shfl_xor(acc.y, off);
            acc.z += __shfl_xor(acc.z, off);
            acc.w += __shfl_xor(acc.w, off);
            sumX  += __shfl_xor(sumX, off);
        }
        sum += sumX;

        float inv = 1.f / sum;
        float4 v;
        v.x = fmaf(acc.x, inv, bc.x); v.y = fmaf(acc.y, inv, bc.y);
        v.z = fmaf(acc.z, inv, bc.z); v.w = fmaf(acc.w, inv, bc.w);
        v.x = (v.x > 0.f) ? v.x : LR_ACT * v.x;
        v.y = (v.y > 0.f) ? v.y : LR_ACT * v.y;
        v.z = (v.z > 0.f) ? v.z : LR_ACT * v.z;
        v.w = (v.w > 0.f) ? v.w : LR_ACT * v.w;

        if (!FUSE_HEAD) {
            if (lane < 16) *(float4*)&hout[(size_t)d * HID + ch] = v;
        } else {
            float t = v.x * wc.x + v.y * wc.y + v.z * wc.z + v.w * wc.w;
            #pragma unroll
            for (int off = 8; off; off >>= 1) t += __shfl_xor(t, off);
            if (lane == 0) out[d] = t + bout[0];
        }
    }
}

extern "C" void kernel_launch(void* const* d_in, const int* in_sizes, int n_in,
                              void* d_out, int out_size, void* d_ws, size_t ws_size,
                              hipStream_t stream)
{
    const float* x      = (const float*)d_in[0];
    const int*   ei     = (const int*)  d_in[1];
    const float* W1     = (const float*)d_in[2];
    const float* a_src1 = (const float*)d_in[3];
    const float* a_dst1 = (const float*)d_in[4];
    const float* b1     = (const float*)d_in[5];
    const float* W2     = (const float*)d_in[6];
    const float* a_src2 = (const float*)d_in[7];
    const float* a_dst2 = (const float*)d_in[8];
    const float* b2     = (const float*)d_in[9];
    const float* W3     = (const float*)d_in[10];
    const float* a_src3 = (const float*)d_in[11];
    const float* a_dst3 = (const float*)d_in[12];
    const float* b3     = (const float*)d_in[13];
    const float* W_out  = (const float*)d_in[14];
    const float* b_out  = (const float*)d_in[15];
    float* out = (float*)d_out;

    const int n = out_size;           // 50000 nodes
    const int E = in_sizes[1] / 2;    // 1.6M edges
    const int NB = (n + 255) >> BSHIFT;   // 196 buckets (<=256)

    const int* src = ei;
    const int* dst = ei + E;

    // workspace layout; bucketed (E u64) ALIASES hA (consumed before gemm1 writes hA)
    float* ws   = (float*)d_ws;
    size_t reg1 = ((size_t)E * 8 > (size_t)n * HID * 4) ? (size_t)E * 2
                                                        : (size_t)n * HID;  // in floats
    float* hA   = ws;                        // n*64 floats (also bucketed E u64)
    float* hB   = hA + reg1;                 // n*64
    float* al_s = hB + (size_t)n * HID;      // n
    float* al_d = al_s + n;                  // n
    int* bucket_counts = (int*)(al_d + n);   // NB
    int* bucket_off    = bucket_counts + NB; // NB+1
    int* cursor        = bucket_off + NB + 1;// NB
    int* offsets       = cursor + NB;        // n+1
    int* sorted_src    = offsets + (n + 1);  // E
    unsigned long long* bucketed = (unsigned long long*)hA;  // E u64 (256B-aligned ws)

    dim3 blk(256);
    const int node_grid  = (n + 3) / 4;
    const int gemm1_grid = (n + 31) / 32;
    const int gemm2_grid = (n + 63) / 64;
    const int scat_grid  = (E + TILE - 1) / TILE;

    // ---- CSR build via bucket sort (graph is layer-invariant) ----
    (void)hipMemsetAsync(bucket_counts, 0, (size_t)NB * sizeof(int), stream);
    bucket_hist_kernel<<<512, blk, 0, stream>>>(dst, bucket_counts, E, NB);
    bucket_scan_kernel<<<1, blk, 0, stream>>>(bucket_counts, bucket_off, cursor,
        offsets, NB, n, E);
    bucket_scatter_kernel<<<scat_grid, blk, 0, stream>>>(src, dst, cursor,
        bucketed, E, NB);
    bucket_sort_kernel<<<NB, blk, 0, stream>>>(bucketed, bucket_off,
        sorted_src, offsets, n);

    // ---- layer 1 (K = 128) ----
    gemm_tile_kernel<128><<<gemm1_grid, blk, 0, stream>>>(x, W1, a_src1, a_dst1,
        hA, al_s, al_d, n);
    node_agg_kernel<false><<<node_grid, blk, 0, stream>>>(offsets, sorted_src,
        al_s, al_d, hA, b1, hB, nullptr, nullptr, nullptr, n);

    // ---- layer 2 (K = 64) ----
    gemm_tile_kernel<64><<<gemm2_grid, blk, 0, stream>>>(hB, W2, a_src2, a_dst2,
        hA, al_s, al_d, n);
    node_agg_kernel<false><<<node_grid, blk, 0, stream>>>(offsets, sorted_src,
        al_s, al_d, hA, b2, hB, nullptr, nullptr, nullptr, n);

    // ---- layer 3 (K = 64) + fused output head ----
    gemm_tile_kernel<64><<<gemm2_grid, blk, 0, stream>>>(hB, W3, a_src3, a_dst3,
        hA, al_s, al_d, n);
    node_agg_kernel<true><<<node_grid, blk, 0, stream>>>(offsets, sorted_src,
        al_s, al_d, hA, b3, nullptr, W_out, b_out, out, n);
}